// Round 8
// baseline (295.193 us; speedup 1.0000x reference)
//
#include <hip/hip_runtime.h>
#include <stdint.h>

#define B 128
#define F 8192
#define H 8192
#define S 4
#define K 32
#define L 3
#define C 100
#define GRID 256   // one block per CU; capacity-guaranteed co-resident

__device__ __forceinline__ int load_threshold(const int* p) {
    int v = *p;
    if (v >= (1 << 23)) v = (int)__int_as_float(v);
    return v;
}

// ---------------------------------------------------------------------------
// Monotonic grid barrier: counter starts at 0 (hipMemsetAsync before launch),
// barrier #p waits for count >= GRID*p. Agent-scope atomics + threadfence
// handle cross-XCD L2 non-coherence (release wb / acquire inv).
// ---------------------------------------------------------------------------
__device__ __forceinline__ void grid_barrier(uint32_t* bar, int phase) {
    __threadfence();                 // push this thread's writes to agent scope
    __syncthreads();
    if (threadIdx.x == 0) {
        __hip_atomic_fetch_add(bar, 1u, __ATOMIC_RELEASE, __HIP_MEMORY_SCOPE_AGENT);
        const uint32_t target = (uint32_t)GRID * (uint32_t)phase;
        while (__hip_atomic_load(bar, __ATOMIC_ACQUIRE, __HIP_MEMORY_SCOPE_AGENT) < target)
            __builtin_amdgcn_s_sleep(2);
    }
    __syncthreads();
    __threadfence();                 // invalidate stale cached lines
}

// ---------------------------------------------------------------------------
// Phase 1: pack x (B,F) float {0,1} -> planar u32 planes xP[w][f], w=b>>5.
// Block covers 32 f; wave = 64 consecutive b; also zeroes d_out.
// ---------------------------------------------------------------------------
__device__ void pack_phase(const float* __restrict__ x, uint32_t* __restrict__ xP,
                           float* __restrict__ out) {
    const int tid = threadIdx.x;
    const int zi = blockIdx.x * 256 + tid;
    if (zi < B * C) out[zi] = 0.0f;

    const int b    = tid & 127;
    const int half = tid >> 7;                  // which 16-f sub-tile
    const int wlo  = ((tid >> 6) & 1) * 2;      // first u32 word for this wave
    const int f0   = blockIdx.x * 32 + half * 16;
    const float4* xr = (const float4*)(x + (size_t)b * F + f0);
#pragma unroll
    for (int j = 0; j < 4; ++j) {
        const float4 v = xr[j];
        const uint64_t m0 = __ballot(v.x > 0.5f);
        const uint64_t m1 = __ballot(v.y > 0.5f);
        const uint64_t m2 = __ballot(v.z > 0.5f);
        const uint64_t m3 = __ballot(v.w > 0.5f);
        if ((tid & 63) == 0) {
            const int f = f0 + 4 * j;
            xP[(size_t)wlo * F + f + 0]       = (uint32_t)m0;
            xP[(size_t)(wlo + 1) * F + f + 0] = (uint32_t)(m0 >> 32);
            xP[(size_t)wlo * F + f + 1]       = (uint32_t)m1;
            xP[(size_t)(wlo + 1) * F + f + 1] = (uint32_t)(m1 >> 32);
            xP[(size_t)wlo * F + f + 2]       = (uint32_t)m2;
            xP[(size_t)(wlo + 1) * F + f + 2] = (uint32_t)(m2 >> 32);
            xP[(size_t)wlo * F + f + 3]       = (uint32_t)m3;
            xP[(size_t)(wlo + 1) * F + f + 3] = (uint32_t)(m3 >> 32);
        }
    }
}

// ---------------------------------------------------------------------------
// Phase 2-4: bit-sliced u32 layer (R7 body). Block = (hg, wb); processes
// w = wb and wb+2 serially, staging isg ONCE (shared across both items).
// wave = segment s; lane = neuron h within the 64-h group.
// ---------------------------------------------------------------------------
__device__ void layer_phase(const uint32_t* __restrict__ prevP,
                            const int* __restrict__ idx,
                            const float* __restrict__ signs,
                            uint32_t* __restrict__ outP, const int thr,
                            uint32_t* tab, uint32_t* isg, uint32_t* fbuf) {
    const int tid  = threadIdx.x;
    const int lane = tid & 63;
    const int sw   = tid >> 6;               // wave = segment
    const int hg   = blockIdx.x & 127;
    const int wb   = blockIdx.x >> 7;        // 0 or 1
    const int h    = hg * 64 + lane;

    // ---- stage idx/sign tiles once (4 segments, contiguous 8 KB each) ----
    {
        const int hrow = tid >> 2;
        const int k0   = (tid & 3) * 8;
#pragma unroll
        for (int s = 0; s < S; ++s) {
            const int4*   ib = (const int4*)(idx   + ((size_t)s * H + hg * 64) * K);
            const float4* sb = (const float4*)(signs + ((size_t)s * H + hg * 64) * K);
            const int4   ia = ib[2 * tid],  ic = ib[2 * tid + 1];
            const float4 sa = sb[2 * tid],  sc = sb[2 * tid + 1];
            uint32_t* dst = isg + s * (64 * 33) + hrow * 33 + k0;
            dst[0] = (uint32_t)ia.x | ((uint32_t)__float_as_int(sa.x) & 0x80000000u);
            dst[1] = (uint32_t)ia.y | ((uint32_t)__float_as_int(sa.y) & 0x80000000u);
            dst[2] = (uint32_t)ia.z | ((uint32_t)__float_as_int(sa.z) & 0x80000000u);
            dst[3] = (uint32_t)ia.w | ((uint32_t)__float_as_int(sa.w) & 0x80000000u);
            dst[4] = (uint32_t)ic.x | ((uint32_t)__float_as_int(sc.x) & 0x80000000u);
            dst[5] = (uint32_t)ic.y | ((uint32_t)__float_as_int(sc.y) & 0x80000000u);
            dst[6] = (uint32_t)ic.z | ((uint32_t)__float_as_int(sc.z) & 0x80000000u);
            dst[7] = (uint32_t)ic.w | ((uint32_t)__float_as_int(sc.w) & 0x80000000u);
        }
    }

#pragma unroll
    for (int it = 0; it < 2; ++it) {
        const int w = wb + 2 * it;
        // ---- stage tab (word-w plane, 32 KiB, coalesced int4) ----
        {
            const int4* src = (const int4*)(prevP + (size_t)w * H);
            int4* dst = (int4*)tab;
#pragma unroll
            for (int i = 0; i < 8; ++i)
                dst[i * 256 + tid] = src[i * 256 + tid];
        }
        __syncthreads();

        uint32_t A[6] = {0, 0, 0, 0, 0, 0};
        uint32_t P[6] = {0, 0, 0, 0, 0, 0};
        const uint32_t* row = isg + sw * (64 * 33) + lane * 33;
#pragma unroll
        for (int jc = 0; jc < K; jc += 8) {
            uint32_t iv[8];
#pragma unroll
            for (int j = 0; j < 8; ++j) iv[j] = row[jc + j];
            uint32_t a[8];
#pragma unroll
            for (int j = 0; j < 8; ++j) a[j] = tab[iv[j] & 0xFFFF];
#pragma unroll
            for (int j = 0; j < 8; ++j) {
                const uint32_t pm = ~(uint32_t)((int32_t)iv[j] >> 31);
                uint32_t c = a[j];
#pragma unroll
                for (int i = 0; i < 6; ++i) { const uint32_t t = A[i]; A[i] = t ^ c; c = t & c; }
                c = a[j] & pm;
#pragma unroll
                for (int i = 0; i < 6; ++i) { const uint32_t t = P[i]; P[i] = t ^ c; c = t & c; }
            }
        }

        // fired = (2P >= A + thr), 7-bit bit-sliced compare
        uint32_t Y[7];
        {
            uint32_t c = 0;
#pragma unroll
            for (int i = 0; i < 7; ++i) {
                const uint32_t ai = (i < 6) ? A[i] : 0u;
                const uint32_t bm = ((thr >> i) & 1) ? 0xFFFFFFFFu : 0u;
                const uint32_t t  = ai ^ bm;
                Y[i] = t ^ c;
                c = (ai & bm) | (t & c);
            }
        }
        uint32_t bw = 0;
#pragma unroll
        for (int i = 0; i < 7; ++i) {
            const uint32_t xx = (i >= 1) ? P[i - 1] : 0u;
            const uint32_t d  = xx ^ Y[i];
            bw = ((~xx) & Y[i]) | ((~d) & bw);
        }
        const uint32_t fired = ~bw;

        fbuf[sw * 64 + lane] = fired;
        __syncthreads();
        if (sw == 0) {
            const uint32_t fo = fbuf[lane] | fbuf[64 + lane] |
                                fbuf[128 + lane] | fbuf[192 + lane];
            outP[(size_t)w * H + h] = fo;
        }
        __syncthreads();   // protect tab/fbuf before next item overwrites
    }
}

// ---------------------------------------------------------------------------
// Phase 5: out[b][c] = sum_l sum_h act[l][b][h] * wout[l][h][c] (R7 body).
// Block runs 2 items; item -> (bg, hc). Wave = one b, lanes = c.
// ---------------------------------------------------------------------------
#define NHC 16
#define HCH (H / NHC)   // 512

__device__ void final_phase(const uint32_t* __restrict__ actP,
                            const float* __restrict__ wout,
                            float* __restrict__ out) {
    const int lane = threadIdx.x & 63;
    const int wid  = threadIdx.x >> 6;
    const int c1 = 64 + lane;
    const bool c1v = (c1 < C);

#pragma unroll
    for (int it = 0; it < 2; ++it) {
        const int item = blockIdx.x + GRID * it;   // 0..511
        const int hc = item & (NHC - 1);
        const int bg = item / NHC;                 // 0..31
        const int b  = bg * 4 + wid;
        const int w32 = b >> 5;
        const int bit = b & 31;

        float acc0 = 0.0f, acc1 = 0.0f;
        for (int l = 0; l < L; ++l) {
            const uint32_t* aT = actP + ((size_t)l * 4 + w32) * H;
            const float* wl = wout + (size_t)l * H * C;
            for (int r = 0; r < HCH / 64; ++r) {
                const int hbase = hc * HCH + r * 64;
                const uint32_t m = aT[hbase + lane];
                uint64_t hm = __ballot((m >> bit) & 1u);
                while (hm) {
                    const int slot = __ffsll((unsigned long long)hm) - 1;
                    hm &= hm - 1;
                    const float* wr = wl + (size_t)(hbase + slot) * C;
                    acc0 += wr[lane];
                    if (c1v) acc1 += wr[c1];
                }
            }
        }
        atomicAdd(&out[b * C + lane], acc0);
        if (c1v) atomicAdd(&out[b * C + c1], acc1);
    }
}

// ---------------------------------------------------------------------------
__global__ __launch_bounds__(256, 1)
void fused_kernel(const float* __restrict__ x,
                  const float* __restrict__ signs0,
                  const float* __restrict__ signsH,
                  const float* __restrict__ wout,
                  const int* __restrict__ idx0,
                  const int* __restrict__ idxH,
                  const int* __restrict__ thrp,
                  float* __restrict__ out,
                  uint32_t* __restrict__ bar,
                  uint32_t* __restrict__ xP,
                  uint32_t* __restrict__ actP) {
    __shared__ uint32_t tab[H];              // 32 KiB
    __shared__ uint32_t isg[S * 64 * 33];    // 33 KiB
    __shared__ uint32_t fbuf[256];           // 1 KiB
    const int thr = load_threshold(thrp);

    pack_phase(x, xP, out);
    grid_barrier(bar, 1);
    layer_phase(xP, idx0, signs0, actP, thr, tab, isg, fbuf);
    grid_barrier(bar, 2);
    layer_phase(actP, idxH, signsH, actP + (size_t)4 * H, thr, tab, isg, fbuf);
    grid_barrier(bar, 3);
    layer_phase(actP + (size_t)4 * H,
                idxH + (size_t)S * H * K, signsH + (size_t)S * H * K,
                actP + (size_t)8 * H, thr, tab, isg, fbuf);
    grid_barrier(bar, 4);
    final_phase(actP, wout, out);
}

// ---------------------------------------------------------------------------
extern "C" void kernel_launch(void* const* d_in, const int* in_sizes, int n_in,
                              void* d_out, int out_size, void* d_ws, size_t ws_size,
                              hipStream_t stream) {
    const float* x      = (const float*)d_in[0];   // (B,F)
    const float* signs0 = (const float*)d_in[1];   // (S,H,K)
    const float* signsH = (const float*)d_in[2];   // (L-1,S,H,K)
    const float* wout   = (const float*)d_in[3];   // (L,H,C)
    const int*   idx0   = (const int*)d_in[4];     // (S,H,K)
    const int*   idxH   = (const int*)d_in[5];     // (L-1,S,H,K)
    const int*   thr    = (const int*)d_in[6];     // scalar
    float* out = (float*)d_out;                    // (B,C)

    // Workspace: [bar 1 KiB][xP u32[4][F] 128 KiB][actP u32[L][4][H] 384 KiB]
    uint32_t* bar  = (uint32_t*)d_ws;
    uint32_t* xP   = (uint32_t*)((char*)d_ws + 1024);
    uint32_t* actP = xP + (size_t)4 * F;

    hipMemsetAsync(bar, 0, 16, stream);            // zero the barrier counter
    fused_kernel<<<GRID, 256, 0, stream>>>(x, signs0, signsH, wout, idx0, idxH,
                                           thr, out, bar, xP, actP);
}

// Round 9
// 123.214 us; speedup vs baseline: 2.3958x; 2.3958x over previous
//
#include <hip/hip_runtime.h>
#include <stdint.h>

#define B 128
#define F 8192
#define H 8192
#define S 4
#define K 32
#define L 3
#define C 100

// ---------------------------------------------------------------------------
// Pack x (B,F) float {0,1} -> PLANAR u32 bit tables xP[w][f], w = b>>5,
// bit = b & 31. Block = 128 threads (thread = b), 32 f per block.
// Also zeroes d_out (fused, saves a launch).
// ---------------------------------------------------------------------------
__global__ void pack_x_kernel(const float* __restrict__ x, uint32_t* __restrict__ xP,
                              float* __restrict__ out) {
    const int zi = blockIdx.x * 128 + threadIdx.x;
    if (zi < B * C) out[zi] = 0.0f;

    const int b = threadIdx.x;           // 0..127
    const int wv = threadIdx.x >> 6;     // wave id (0,1)
    const int f0 = blockIdx.x * 32;
    const float4* xr = (const float4*)(x + (size_t)b * F + f0);
    for (int j = 0; j < 8; ++j) {
        const float4 v = xr[j];
        const uint64_t m0 = __ballot(v.x > 0.5f);
        const uint64_t m1 = __ballot(v.y > 0.5f);
        const uint64_t m2 = __ballot(v.z > 0.5f);
        const uint64_t m3 = __ballot(v.w > 0.5f);
        if ((threadIdx.x & 63) == 0) {
            const int f = f0 + 4 * j;
            uint32_t* lo = xP + (size_t)(2 * wv) * F;
            uint32_t* hi = xP + (size_t)(2 * wv + 1) * F;
            lo[f + 0] = (uint32_t)m0;  hi[f + 0] = (uint32_t)(m0 >> 32);
            lo[f + 1] = (uint32_t)m1;  hi[f + 1] = (uint32_t)(m1 >> 32);
            lo[f + 2] = (uint32_t)m2;  hi[f + 2] = (uint32_t)(m2 >> 32);
            lo[f + 3] = (uint32_t)m3;  hi[f + 3] = (uint32_t)(m3 >> 32);
        }
    }
}

__device__ __forceinline__ int load_threshold(const int* p) {
    // threshold is a tiny int; guard against the harness storing it as f32 bits
    int v = *p;
    if (v >= (1 << 23)) v = (int)__int_as_float(v);
    return v;
}

// ---------------------------------------------------------------------------
// BIT-SLICED u32 layer: prevP[w][hprev] (planar u32, w=0..3) -> outP[w][h].
// lane = neuron h (64 h per wave); the 32-batch mask word is per-lane DATA.
// Block = 256 = 4 waves; wave = segment s. blockIdx = hg*4 + w.
// isg rows stride 40 u32 (160 B): uint4 reads/writes 16B-aligned,
// bank-balanced. Gather loop: batch-8 ds_read_b32 gathers + u32 carry-save
// counters A=sum a, P=sum a&pos. fired = (2P >= A+thr) bit-sliced;
// OR across segments via LDS. 512 blocks, 2 blocks/CU (73 KiB LDS).
// ---------------------------------------------------------------------------
#define ISG_STRIDE 40

__global__ void layer_kernel(const uint32_t* __restrict__ prevP,
                             const int* __restrict__ idx,
                             const float* __restrict__ signs,
                             uint32_t* __restrict__ outP,
                             const int* __restrict__ thrp) {
    __shared__ uint32_t tab[H];                       // 32 KiB
    __shared__ uint32_t isg[S * 64 * ISG_STRIDE];     // 40 KiB
    __shared__ uint32_t fbuf[256];                    // 1 KiB
    const int tid  = threadIdx.x;
    const int lane = tid & 63;
    const int sw   = tid >> 6;               // wave = segment
    const int w    = blockIdx.x & 3;
    const int hg   = blockIdx.x >> 2;
    const int h    = hg * 64 + lane;
    const int thr  = load_threshold(thrp);

    // ---- stage tab (word-w plane, 32 KiB, coalesced int4) ----
    {
        const int4* src = (const int4*)(prevP + (size_t)w * H);
        int4* dst = (int4*)tab;
#pragma unroll
        for (int i = 0; i < 8; ++i)
            dst[i * 256 + tid] = src[i * 256 + tid];
    }
    // ---- stage idx/sign tiles: per s, 2048 ints contiguous ----
    // thread t handles 8 elems: h-row = t/4, k0 = 8*(t%4); uint4 stores.
    {
        const int hrow = tid >> 2;
        const int k0   = (tid & 3) * 8;
#pragma unroll
        for (int s = 0; s < S; ++s) {
            const int4*   ib = (const int4*)(idx   + ((size_t)s * H + hg * 64) * K);
            const float4* sb = (const float4*)(signs + ((size_t)s * H + hg * 64) * K);
            const int4   ia = ib[2 * tid],  ic = ib[2 * tid + 1];
            const float4 sa = sb[2 * tid],  sc = sb[2 * tid + 1];
            uint4* dst = (uint4*)(isg + s * (64 * ISG_STRIDE) + hrow * ISG_STRIDE + k0);
            uint4 p0, p1;
            p0.x = (uint32_t)ia.x | ((uint32_t)__float_as_int(sa.x) & 0x80000000u);
            p0.y = (uint32_t)ia.y | ((uint32_t)__float_as_int(sa.y) & 0x80000000u);
            p0.z = (uint32_t)ia.z | ((uint32_t)__float_as_int(sa.z) & 0x80000000u);
            p0.w = (uint32_t)ia.w | ((uint32_t)__float_as_int(sa.w) & 0x80000000u);
            p1.x = (uint32_t)ic.x | ((uint32_t)__float_as_int(sc.x) & 0x80000000u);
            p1.y = (uint32_t)ic.y | ((uint32_t)__float_as_int(sc.y) & 0x80000000u);
            p1.z = (uint32_t)ic.z | ((uint32_t)__float_as_int(sc.z) & 0x80000000u);
            p1.w = (uint32_t)ic.w | ((uint32_t)__float_as_int(sc.w) & 0x80000000u);
            dst[0] = p0;
            dst[1] = p1;
        }
    }
    __syncthreads();

    // ---- gather + bit-sliced accumulate ----
    uint32_t A[6] = {0, 0, 0, 0, 0, 0};      // sum of a      (<=32)
    uint32_t P[6] = {0, 0, 0, 0, 0, 0};      // sum of a&pos  (<=32)
    const uint4* row4 = (const uint4*)(isg + sw * (64 * ISG_STRIDE) + lane * ISG_STRIDE);
#pragma unroll
    for (int c = 0; c < 4; ++c) {
        const uint4 r0 = row4[2 * c];
        const uint4 r1 = row4[2 * c + 1];
        const uint32_t iv[8] = {r0.x, r0.y, r0.z, r0.w, r1.x, r1.y, r1.z, r1.w};
        uint32_t a[8];
#pragma unroll
        for (int j = 0; j < 8; ++j) a[j] = tab[iv[j] & 0xFFFFu];  // batch gathers
#pragma unroll
        for (int j = 0; j < 8; ++j) {
            const uint32_t pm = ~(uint32_t)((int32_t)iv[j] >> 31); // ~0 if pos
            uint32_t cc = a[j];
#pragma unroll
            for (int i = 0; i < 6; ++i) { const uint32_t t = A[i]; A[i] = t ^ cc; cc = t & cc; }
            cc = a[j] & pm;
#pragma unroll
            for (int i = 0; i < 6; ++i) { const uint32_t t = P[i]; P[i] = t ^ cc; cc = t & cc; }
        }
    }

    // ---- fired = (2P >= A + thr), 7-bit bit-sliced compare ----
    uint32_t Y[7];
    {
        uint32_t c = 0;
#pragma unroll
        for (int i = 0; i < 7; ++i) {
            const uint32_t ai = (i < 6) ? A[i] : 0u;
            const uint32_t bm = ((thr >> i) & 1) ? 0xFFFFFFFFu : 0u;
            const uint32_t t  = ai ^ bm;
            Y[i] = t ^ c;
            c = (ai & bm) | (t & c);
        }
    }
    uint32_t bw = 0;
#pragma unroll
    for (int i = 0; i < 7; ++i) {
        const uint32_t xx = (i >= 1) ? P[i - 1] : 0u;
        const uint32_t d  = xx ^ Y[i];
        bw = ((~xx) & Y[i]) | ((~d) & bw);
    }
    const uint32_t fired = ~bw;

    // ---- OR across the 4 segment-waves ----
    fbuf[sw * 64 + lane] = fired;
    __syncthreads();
    if (sw == 0) {
        const uint32_t f = fbuf[lane] | fbuf[64 + lane] |
                           fbuf[128 + lane] | fbuf[192 + lane];
        outP[(size_t)w * H + h] = f;             // coalesced 4B stores
    }
}

// ---------------------------------------------------------------------------
// out[b][c] = sum_l sum_h act[l][b][h] * wout[l][h][c], act in {0,1}.
// Wave = one b; lanes = c (acc in 2 VGPRs: c=lane, c=lane+64).
// Grid = 32 b-groups x NHC h-chunks; block = 256 (4 waves = 4 consecutive b).
// NHC=32 -> 1024 blocks = 4 blocks/CU = 16 waves/CU for latency hiding;
// each wave walks ~23 set bits (l=0 density ~9%, l1/l2 ~0).
// Planar u32 masks: actP[(l*4 + (b>>5))*H + h], bit = b & 31.
// ---------------------------------------------------------------------------
#define NHC 32
#define HCH (H / NHC)   // 256 h per chunk

__global__ void final_kernel(const uint32_t* __restrict__ actP,
                             const float* __restrict__ wout,
                             float* __restrict__ out) {
    const int lane = threadIdx.x & 63;
    const int wid  = threadIdx.x >> 6;          // 0..3
    const int hc   = blockIdx.x & (NHC - 1);
    const int bg   = blockIdx.x / NHC;          // 0..31
    const int b    = bg * 4 + wid;              // wave-uniform
    const int w32  = b >> 5;                    // uniform within wave
    const int bit  = b & 31;

    float acc0 = 0.0f, acc1 = 0.0f;
    const int c1 = 64 + lane;
    const bool c1v = (c1 < C);

    for (int l = 0; l < L; ++l) {
        const uint32_t* aT = actP + ((size_t)l * 4 + w32) * H;
        const float* wl = wout + (size_t)l * H * C;
        for (int r = 0; r < HCH / 64; ++r) {
            const int hbase = hc * HCH + r * 64;
            const uint32_t m = aT[hbase + lane];
            uint64_t hm = __ballot((m >> bit) & 1u);
            while (hm) {
                const int slot = __ffsll((unsigned long long)hm) - 1;
                hm &= hm - 1;
                const float* wr = wl + (size_t)(hbase + slot) * C;
                acc0 += wr[lane];
                if (c1v) acc1 += wr[c1];
            }
        }
    }
    atomicAdd(&out[b * C + lane], acc0);
    if (c1v) atomicAdd(&out[b * C + c1], acc1);
}

// ---------------------------------------------------------------------------
extern "C" void kernel_launch(void* const* d_in, const int* in_sizes, int n_in,
                              void* d_out, int out_size, void* d_ws, size_t ws_size,
                              hipStream_t stream) {
    const float* x      = (const float*)d_in[0];   // (B,F)
    const float* signs0 = (const float*)d_in[1];   // (S,H,K)
    const float* signsH = (const float*)d_in[2];   // (L-1,S,H,K)
    const float* wout   = (const float*)d_in[3];   // (L,H,C)
    const int*   idx0   = (const int*)d_in[4];     // (S,H,K)
    const int*   idxH   = (const int*)d_in[5];     // (L-1,S,H,K)
    const int*   thr    = (const int*)d_in[6];     // scalar
    float* out = (float*)d_out;                    // (B,C)

    // Workspace (planar u32): xP [4][F] (128 KiB), actP [L][4][H] (384 KiB)
    uint32_t* xP   = (uint32_t*)d_ws;
    uint32_t* actP = xP + (size_t)4 * F;

    // pack x + zero out (fused)
    pack_x_kernel<<<F / 32, 128, 0, stream>>>(x, xP, out);

    // layers: grid = 128 h-groups x 4 words = 512 blocks, 4 segment-waves each
    layer_kernel<<<512, 256, 0, stream>>>(xP, idx0, signs0, actP, thr);
    layer_kernel<<<512, 256, 0, stream>>>(actP, idxH, signsH,
                                          actP + (size_t)4 * H, thr);
    layer_kernel<<<512, 256, 0, stream>>>(actP + (size_t)4 * H,
                                          idxH + (size_t)S * H * K,
                                          signsH + (size_t)S * H * K,
                                          actP + (size_t)8 * H, thr);

    final_kernel<<<32 * NHC, 256, 0, stream>>>(actP, wout, out);
}